// Round 12
// baseline (779.865 us; speedup 1.0000x reference)
//
#include <hip/hip_runtime.h>

#define N_NODES 50000
#define N_EDGES 800000
#define N_GRAPHS 100
#define FIN_DIM 74
#define K0 96              // layer-0 K (padded), 6 slices of 16
#define H_DIM 256          // hidden width, 8 slices of 32
#define EG 3125            // N_EDGES / 256
#define XC_BLKS 9375       // N_NODES*48/256 (float2-vectorized xconv)
#define WCONV_BLKS 608     // (256*96 + 2*256*256)/256
#define AGG0_BLKS 3128     // 391 node-groups * 8 slices
#define AGGH_BLKS 6256     // 782 * 8
#define GEMM_BLKS 782      // 391 m-tiles * 2 n-tiles
#define POOL_BLKS 782
#define SCAN_BLOCKS 196

typedef float f32x4 __attribute__((ext_vector_type(4)));
typedef float f32x2 __attribute__((ext_vector_type(2)));
typedef unsigned int u32x4 __attribute__((ext_vector_type(4)));
typedef unsigned short us2 __attribute__((ext_vector_type(2)));
typedef unsigned short us8 __attribute__((ext_vector_type(8)));
typedef __bf16 bf16x8 __attribute__((ext_vector_type(8)));

__device__ __forceinline__ unsigned short f2bf(float x) {
    unsigned u = __builtin_bit_cast(unsigned, x);
    u += 0x7fff + ((u >> 16) & 1);
    return (unsigned short)(u >> 16);
}
__device__ __forceinline__ float bf2f(unsigned short h) {
    return __builtin_bit_cast(float, (unsigned)h << 16);
}
__device__ __forceinline__ void acc8(float* a, us8 v) {
    u32x4 w = __builtin_bit_cast(u32x4, v);
    #pragma unroll
    for (int i = 0; i < 4; ++i) {
        a[2 * i]     += __builtin_bit_cast(float, w[i] << 16);
        a[2 * i + 1] += __builtin_bit_cast(float, w[i] & 0xffff0000u);
    }
}
__device__ __forceinline__ void acc8s(float* a, us8 v, float d) {
    u32x4 w = __builtin_bit_cast(u32x4, v);
    #pragma unroll
    for (int i = 0; i < 4; ++i) {
        a[2 * i]     += __builtin_bit_cast(float, w[i] << 16) * d;
        a[2 * i + 1] += __builtin_bit_cast(float, w[i] & 0xffff0000u) * d;
    }
}

// ================= device bodies =================

__device__ __forceinline__ void hist_body(int bid, const int* __restrict__ src,
                                          const int* __restrict__ dst,
                                          int* __restrict__ cs, int* __restrict__ fc,
                                          int* __restrict__ rk) {
    int e = bid * 256 + threadIdx.x;
    if (e < N_EDGES) {
        rk[e] = atomicAdd(&fc[dst[e]], 1);
        atomicAdd(&cs[src[e]], 1);
    }
}

__device__ __forceinline__ void scat_body(int bid, const int* __restrict__ src,
                                          const int* __restrict__ dst,
                                          const int* __restrict__ rp,
                                          const int* __restrict__ rk,
                                          int* __restrict__ col) {
    int e = bid * 256 + threadIdx.x;
    if (e < N_EDGES) {
        int d = dst[e];
        col[rp[d] + rk[e]] = src[e];
    }
}

// x -> bf16 slice-major [6][N][16], UNSCALED (dso applied in layer-0 agg)
__device__ __forceinline__ void xconv_body(int bid, const float* __restrict__ x,
                                           unsigned short* __restrict__ xp) {
    int id = bid * 256 + threadIdx.x;           // over N*48 pairs
    int n = id / 48, f = (id - n * 48) * 2;     // f even, 0..94
    float v0 = 0.f, v1 = 0.f;
    if (f < FIN_DIM) {                          // f<=72 -> f+1<=73<74: both valid
        f32x2 t = *(const f32x2*)&x[(size_t)n * FIN_DIM + f];
        v0 = t[0]; v1 = t[1];
    }
    us2 r = { f2bf(v0), f2bf(v1) };
    *(us2*)&xp[(size_t)(f >> 4) * (N_NODES * 16) + (size_t)n * 16 + (f & 15)] = r;
}

__device__ __forceinline__ void wconv_body(int bid, const float* __restrict__ W0,
                                           const float* __restrict__ W1,
                                           const float* __restrict__ W2,
                                           unsigned short* __restrict__ Wt) {
    int id = bid * 256 + threadIdx.x;
    if (id < 256 * 96) {
        int n = id / 96, k = id - n * 96;
        float v = (k < FIN_DIM) ? W0[(size_t)k * H_DIM + n] : 0.f;
        Wt[id] = f2bf(v);
    } else if (id < 256 * 96 + 65536) {
        int id2 = id - 256 * 96;
        int n = id2 >> 8, k = id2 & 255;
        Wt[id] = f2bf(W1[(size_t)k * H_DIM + n]);
    } else {
        int id3 = id - 256 * 96 - 65536;
        int n = id3 >> 8, k = id3 & 255;
        Wt[id] = f2bf(W2[(size_t)k * H_DIM + n]);
    }
}

// XCD-sliced aggregate, ILP-8. DSO: gather per-edge dso[s] (layer 0 only).
template<int SW, int NACT, int NSL, bool DSO>
__device__ __forceinline__ void agg_body(int abid, int cg,
                                         const unsigned short* __restrict__ h,
                                         const float* __restrict__ dso,
                                         const int* __restrict__ rp,
                                         const int* __restrict__ col,
                                         unsigned short* __restrict__ A) {
    const int CPB = SW / 8;
    const int NPB = 256 / CPB;
    if (cg >= NSL) return;
    int slot = threadIdx.x & (CPB - 1);
    int n = (abid >> 3) * NPB + threadIdx.x / CPB;
    if (n >= N_NODES) return;
    unsigned short* dst = A + (size_t)cg * (N_NODES * SW) + (size_t)n * SW + slot * 8;
    if (cg >= NACT) { us8 z = {}; *(us8*)dst = z; return; }
    const unsigned short* hs = h + (size_t)cg * (N_NODES * SW) + slot * 8;
    int beg = rp[n], end = rp[n + 1];
    float a[8] = {};
    int j = beg;
    // 8-deep ILP main loop
    for (; j + 7 < end; j += 8) {
        int s[8];
        #pragma unroll
        for (int t = 0; t < 8; ++t) s[t] = col[j + t];
        us8 v[8];
        #pragma unroll
        for (int t = 0; t < 8; ++t) v[t] = *(const us8*)(hs + (size_t)s[t] * SW);
        if (DSO) {
            float d[8];
            #pragma unroll
            for (int t = 0; t < 8; ++t) d[t] = dso[s[t]];
            #pragma unroll
            for (int t = 0; t < 8; ++t) acc8s(a, v[t], d[t]);
        } else {
            #pragma unroll
            for (int t = 0; t < 8; ++t) acc8(a, v[t]);
        }
    }
    // 4-deep
    for (; j + 3 < end; j += 4) {
        int s[4];
        #pragma unroll
        for (int t = 0; t < 4; ++t) s[t] = col[j + t];
        us8 v[4];
        #pragma unroll
        for (int t = 0; t < 4; ++t) v[t] = *(const us8*)(hs + (size_t)s[t] * SW);
        if (DSO) {
            #pragma unroll
            for (int t = 0; t < 4; ++t) acc8s(a, v[t], dso[s[t]]);
        } else {
            #pragma unroll
            for (int t = 0; t < 4; ++t) acc8(a, v[t]);
        }
    }
    // scalar tail
    for (; j < end; ++j) {
        int s = col[j];
        us8 v = *(const us8*)(hs + (size_t)s * SW);
        if (DSO) acc8s(a, v, dso[s]);
        else     acc8(a, v);
    }
    us8 r;
    #pragma unroll
    for (int i = 0; i < 8; ++i) r[i] = f2bf(a[i]);
    *(us8*)dst = r;
}

__device__ __forceinline__ void pool_body(int nb, const unsigned short* __restrict__ h,
                                          const int* __restrict__ gid,
                                          float* __restrict__ pool) {
    int n0 = nb * 64;
    int f = threadIdx.x;
    const unsigned short* hf = h + (size_t)(f >> 5) * (N_NODES * 32) + (f & 31);
    int end = min(n0 + 64, N_NODES);
    float acc = 0.0f;
    int gcur = gid[n0];
    for (int i = n0; i < end; ++i) {
        int g = gid[i];
        if (g != gcur) {
            atomicAdd(&pool[(size_t)gcur * H_DIM + f], acc);
            acc = 0.0f;
            gcur = g;
        }
        acc += bf2f(hf[(size_t)i * 32]);
    }
    atomicAdd(&pool[(size_t)gcur * H_DIM + f], acc);
}

// MFMA GEMM (R9-proven, full B staging)
template<int K, int SW>
__device__ __forceinline__ void gemm_body(int id, const unsigned short* __restrict__ A,
                                          const unsigned short* __restrict__ Wt,
                                          const float* __restrict__ bias,
                                          const float* __restrict__ dsi,
                                          const float* __restrict__ scale,
                                          unsigned short* __restrict__ C,
                                          unsigned short* smem) {
    unsigned short (*Ah)[40] = (unsigned short(*)[40])smem;
    unsigned short (*Bh)[40] = (unsigned short(*)[40])(smem + 128 * 40);
    const int M = N_NODES;

    int tid = threadIdx.x;
    int lane = tid & 63, wid = tid >> 6;
    int wm = (wid >> 1) * 64, wn = (wid & 1) * 64;
    int bm = (id >> 1) * 128, bn = (id & 1) * 128;

    f32x4 acc[4][4] = {};
    int r0 = wm + (lane & 15);
    int c0 = wn + (lane & 15);
    int kA = (lane >> 4) * 8;

    for (int k0 = 0; k0 < K; k0 += 32) {
        #pragma unroll
        for (int i = 0; i < 2; ++i) {
            int q = tid + i * 256;
            int row = q >> 2, k8 = (q & 3) * 8;
            int gm = bm + row;
            int kk = k0 + k8;
            us8 v = {};
            if (gm < M)
                v = *(const us8*)(A + (size_t)(kk / SW) * ((size_t)N_NODES * SW)
                                    + (size_t)gm * SW + (kk % SW));
            *(us8*)&Ah[row][k8] = v;
        }
        {
            int colx = tid & 127, kg = tid >> 7;
            const unsigned short* wsrc = Wt + (size_t)(bn + colx) * K + k0 + kg * 16;
            us8 w0 = *(const us8*)(wsrc);
            us8 w1 = *(const us8*)(wsrc + 8);
            *(us8*)&Bh[colx][kg * 16] = w0;
            *(us8*)&Bh[colx][kg * 16 + 8] = w1;
        }
        __syncthreads();

        bf16x8 ah[4], bh[4];
        #pragma unroll
        for (int m = 0; m < 4; ++m)
            ah[m] = __builtin_bit_cast(bf16x8, *(const us8*)&Ah[r0 + m * 16][kA]);
        #pragma unroll
        for (int n = 0; n < 4; ++n)
            bh[n] = __builtin_bit_cast(bf16x8, *(const us8*)&Bh[c0 + n * 16][kA]);

        #pragma unroll
        for (int m = 0; m < 4; ++m)
            #pragma unroll
            for (int n = 0; n < 4; ++n)
                acc[m][n] = __builtin_amdgcn_mfma_f32_16x16x32_bf16(ah[m], bh[n], acc[m][n], 0, 0, 0);
        __syncthreads();
    }

    int rowq = (lane >> 4) * 4;
    #pragma unroll
    for (int n = 0; n < 4; ++n) {
        int gn = bn + wn + n * 16 + (lane & 15);
        float bv = bias[gn];
        unsigned short* cs = C + (size_t)(gn >> 5) * (N_NODES * 32) + (gn & 31);
        #pragma unroll
        for (int m = 0; m < 4; ++m) {
            #pragma unroll
            for (int j = 0; j < 4; ++j) {
                int gm = bm + wm + m * 16 + rowq + j;
                if (gm < M) {
                    float r = fmaxf(acc[m][n][j] * dsi[gm] + bv, 0.0f);
                    if (scale) r *= scale[gm];
                    cs[(size_t)gm * 32] = f2bf(r);
                }
            }
        }
    }
}

// ================= kernels =================

__device__ __forceinline__ int block_excl_scan(int v, int* wsums) {
    int lane = threadIdx.x & 63, w = threadIdx.x >> 6;
    int x = v;
    #pragma unroll
    for (int ofs = 1; ofs < 64; ofs <<= 1) {
        int y = __shfl_up(x, ofs, 64);
        if (lane >= ofs) x += y;
    }
    if (lane == 63) wsums[w] = x;
    __syncthreads();
    int wo = 0;
    #pragma unroll
    for (int k = 0; k < 4; ++k) if (k < w) wo += wsums[k];
    return wo + x - v;
}

// histL || histR || wconv || xconvL || xconvR (riders ~free under atomic latency)
__global__ void k_hist2(const int* __restrict__ srcL, const int* __restrict__ dstL,
                        int* __restrict__ csL, int* __restrict__ fcL, int* __restrict__ rkL,
                        const int* __restrict__ srcR, const int* __restrict__ dstR,
                        int* __restrict__ csR, int* __restrict__ fcR, int* __restrict__ rkR,
                        const float* __restrict__ W0, const float* __restrict__ W1,
                        const float* __restrict__ W2, unsigned short* __restrict__ Wt,
                        const float* __restrict__ xL, unsigned short* __restrict__ xpL,
                        const float* __restrict__ xR, unsigned short* __restrict__ xpR) {
    int bid = blockIdx.x;
    if (bid < EG)                                hist_body(bid, srcL, dstL, csL, fcL, rkL);
    else if (bid < 2 * EG)                       hist_body(bid - EG, srcR, dstR, csR, fcR, rkR);
    else if (bid < 2 * EG + WCONV_BLKS)          wconv_body(bid - 2 * EG, W0, W1, W2, Wt);
    else if (bid < 2 * EG + WCONV_BLKS + XC_BLKS)
        xconv_body(bid - 2 * EG - WCONV_BLKS, xL, xpL);
    else
        xconv_body(bid - 2 * EG - WCONV_BLKS - XC_BLKS, xR, xpR);
}

__global__ void deg_scan1_kernel(const int* __restrict__ csL, const int* __restrict__ fcL,
                                 float* __restrict__ dsoL, float* __restrict__ dsiL,
                                 int* __restrict__ rpL, int* __restrict__ bsL,
                                 const int* __restrict__ csR, const int* __restrict__ fcR,
                                 float* __restrict__ dsoR, float* __restrict__ dsiR,
                                 int* __restrict__ rpR, int* __restrict__ bsR) {
    const int* cs = blockIdx.y ? csR : csL;
    const int* fc = blockIdx.y ? fcR : fcL;
    float* dso = blockIdx.y ? dsoR : dsoL;
    float* dsi = blockIdx.y ? dsiR : dsiL;
    int* rp = blockIdx.y ? rpR : rpL;
    int* bs = blockIdx.y ? bsR : bsL;
    __shared__ int ws[4];
    int i = blockIdx.x * 256 + threadIdx.x;
    int v = 0;
    if (i < N_NODES) {
        dso[i] = rsqrtf(fmaxf((float)cs[i], 1.0f));
        v = fc[i];
        dsi[i] = rsqrtf(fmaxf((float)v, 1.0f));
    }
    int ex = block_excl_scan(v, ws);
    if (i < N_NODES) rp[i] = ex;
    if (threadIdx.x == 255) bs[blockIdx.x] = ex + v;
}

__global__ void scan2_kernel(int* __restrict__ bsL, int* __restrict__ bsR, int nb) {
    int* bs = blockIdx.y ? bsR : bsL;
    __shared__ int ws[4];
    int i = threadIdx.x;
    int v = (i < nb) ? bs[i] : 0;
    int ex = block_excl_scan(v, ws);
    __syncthreads();
    if (i < nb) bs[i] = ex;
}

__global__ void scan3_kernel(int* __restrict__ rpL, const int* __restrict__ bsL,
                             int* __restrict__ rpR, const int* __restrict__ bsR) {
    int* rp = blockIdx.y ? rpR : rpL;
    const int* bs = blockIdx.y ? bsR : bsL;
    int i = blockIdx.x * 256 + threadIdx.x;
    if (i < N_NODES) rp[i] += bs[blockIdx.x];
    if (i == 0) rp[N_NODES] = N_EDGES;
}

// scatL || scatR
__global__ void k_scat2(const int* __restrict__ srcL, const int* __restrict__ dstL,
                        const int* __restrict__ rpL, const int* __restrict__ rkL,
                        int* __restrict__ colL,
                        const int* __restrict__ srcR, const int* __restrict__ dstR,
                        const int* __restrict__ rpR, const int* __restrict__ rkR,
                        int* __restrict__ colR) {
    int bid = blockIdx.x;
    if (bid < EG) scat_body(bid, srcL, dstL, rpL, rkL, colL);
    else          scat_body(bid - EG, srcR, dstR, rpR, rkR, colR);
}

// layer-0 agg pair (with per-edge dso gather)
__global__ void fuse_agg2_l0(const unsigned short* __restrict__ hL, const float* __restrict__ dsoL,
                             const int* __restrict__ rpL, const int* __restrict__ colL,
                             unsigned short* __restrict__ AL,
                             const unsigned short* __restrict__ hR, const float* __restrict__ dsoR,
                             const int* __restrict__ rpR, const int* __restrict__ colR,
                             unsigned short* __restrict__ AR) {
    int bid = blockIdx.x;
    if (bid < AGG0_BLKS) agg_body<16, 5, 6, true>(bid, bid & 7, hL, dsoL, rpL, colL, AL);
    else {
        int lb = bid - AGG0_BLKS;
        agg_body<16, 5, 6, true>(lb, lb & 7, hR, dsoR, rpR, colR, AR);
    }
}

// hidden agg pair (h pre-scaled by dso via gemm epilogue)
__global__ void fuse_agg2_h(const unsigned short* __restrict__ hL, const int* __restrict__ rpL,
                            const int* __restrict__ colL, unsigned short* __restrict__ AL,
                            const unsigned short* __restrict__ hR, const int* __restrict__ rpR,
                            const int* __restrict__ colR, unsigned short* __restrict__ AR) {
    int bid = blockIdx.x;
    if (bid < AGGH_BLKS) agg_body<32, 8, 8, false>(bid, bid & 7, hL, nullptr, rpL, colL, AL);
    else {
        int lb = bid - AGGH_BLKS;
        agg_body<32, 8, 8, false>(lb, lb & 7, hR, nullptr, rpR, colR, AR);
    }
}

template<int K, int SW>
__global__ __launch_bounds__(256) void gemm_pair2(
        const unsigned short* __restrict__ AL, const float* __restrict__ dsiL,
        const float* __restrict__ scL, unsigned short* __restrict__ CL,
        const unsigned short* __restrict__ AR, const float* __restrict__ dsiR,
        const float* __restrict__ scR, unsigned short* __restrict__ CR,
        const unsigned short* __restrict__ Wt, const float* __restrict__ bias) {
    __shared__ unsigned short smem[2 * 128 * 40];
    int bid = blockIdx.x;
    if (bid < GEMM_BLKS) gemm_body<K, SW>(bid, AL, Wt, bias, dsiL, scL, CL, smem);
    else                 gemm_body<K, SW>(bid - GEMM_BLKS, AR, Wt, bias, dsiR, scR, CR, smem);
}

__global__ void pool2_kernel(const unsigned short* __restrict__ hL, const int* __restrict__ gidL,
                             float* __restrict__ poolL,
                             const unsigned short* __restrict__ hR, const int* __restrict__ gidR,
                             float* __restrict__ poolR) {
    int bid = blockIdx.x;
    if (bid < POOL_BLKS) pool_body(bid, hL, gidL, poolL);
    else                 pool_body(bid - POOL_BLKS, hR, gidR, poolR);
}

__global__ __launch_bounds__(256) void mlp_kernel(
        const float* __restrict__ pl, const float* __restrict__ pr,
        const float* __restrict__ Wf1, const float* __restrict__ bf1,
        const float* __restrict__ Wf2, const float* __restrict__ bf2,
        float* __restrict__ out) {
    __shared__ float z[512];
    __shared__ float red[256];
    int g = blockIdx.x, tid = threadIdx.x;
    z[tid] = pl[(size_t)g * H_DIM + tid];
    z[tid + 256] = pr[(size_t)g * H_DIM + tid];
    __syncthreads();
    float t = bf1[tid];
    #pragma unroll 8
    for (int k = 0; k < 512; ++k) t += z[k] * Wf1[(size_t)k * H_DIM + tid];
    t = fmaxf(t, 0.0f);
    red[tid] = t * Wf2[tid];
    __syncthreads();
    for (int ofs = 128; ofs > 0; ofs >>= 1) {
        if (tid < ofs) red[tid] += red[tid + ofs];
        __syncthreads();
    }
    if (tid == 0) out[g] = red[0] + bf2[0];
}

// ================= driver =================

extern "C" void kernel_launch(void* const* d_in, const int* in_sizes, int n_in,
                              void* d_out, int out_size, void* d_ws, size_t ws_size,
                              hipStream_t stream) {
    const float* xl   = (const float*)d_in[0];
    const float* xr   = (const float*)d_in[1];
    const int* src_l  = (const int*)d_in[2];
    const int* dst_l  = (const int*)d_in[3];
    const int* src_r  = (const int*)d_in[4];
    const int* dst_r  = (const int*)d_in[5];
    const int* gid_l  = (const int*)d_in[6];
    const int* gid_r  = (const int*)d_in[7];
    const float* W0   = (const float*)d_in[8];
    const float* b0   = (const float*)d_in[9];
    const float* W1   = (const float*)d_in[10];
    const float* b1   = (const float*)d_in[11];
    const float* W2   = (const float*)d_in[12];
    const float* b2   = (const float*)d_in[13];
    const float* Wf1  = (const float*)d_in[14];
    const float* bf1  = (const float*)d_in[15];
    const float* Wf2  = (const float*)d_in[16];
    const float* bf2  = (const float*)d_in[17];
    float* out = (float*)d_out;
    (void)in_sizes; (void)n_in; (void)out_size; (void)ws_size;

    size_t off = 0;
    auto carve = [&](size_t bytes) {
        void* p = (char*)d_ws + off;
        off += (bytes + 255) & ~(size_t)255;
        return p;
    };
    const size_t NB4 = (size_t)N_NODES * 4;

    // zero zone (single memset)
    char* zstart = (char*)d_ws;
    int*   cs_l   = (int*)carve(NB4);
    int*   fc_l   = (int*)carve(NB4);
    int*   cs_r   = (int*)carve(NB4);
    int*   fc_r   = (int*)carve(NB4);
    float* pool_l = (float*)carve((size_t)N_GRAPHS * H_DIM * 4);
    float* pool_r = (float*)carve((size_t)N_GRAPHS * H_DIM * 4);
    size_t zbytes = off;

    float* dso_l = (float*)carve(NB4);
    float* dsi_l = (float*)carve(NB4);
    float* dso_r = (float*)carve(NB4);
    float* dsi_r = (float*)carve(NB4);
    int*   rp_l  = (int*)carve((size_t)(N_NODES + 1) * 4);
    int*   rp_r  = (int*)carve((size_t)(N_NODES + 1) * 4);
    int*   col_l = (int*)carve((size_t)N_EDGES * 4);
    int*   col_r = (int*)carve((size_t)N_EDGES * 4);
    int*   rk_l  = (int*)carve((size_t)N_EDGES * 4);
    int*   rk_r  = (int*)carve((size_t)N_EDGES * 4);
    int*   bs_l  = (int*)carve((size_t)SCAN_BLOCKS * 4);
    int*   bs_r  = (int*)carve((size_t)SCAN_BLOCKS * 4);

    unsigned short* Wt    = (unsigned short*)carve((size_t)(256 * 96 + 2 * 65536) * 2);
    unsigned short* Wt0   = Wt;
    unsigned short* Wt1   = Wt + 256 * 96;
    unsigned short* Wt2   = Wt + 256 * 96 + 65536;
    unsigned short* xp_l  = (unsigned short*)carve((size_t)N_NODES * 96 * 2);
    unsigned short* xp_r  = (unsigned short*)carve((size_t)N_NODES * 96 * 2);
    unsigned short* bufA_l = (unsigned short*)carve((size_t)N_NODES * H_DIM * 2);
    unsigned short* bufA_r = (unsigned short*)carve((size_t)N_NODES * H_DIM * 2);
    unsigned short* bufH_l = (unsigned short*)carve((size_t)N_NODES * H_DIM * 2);
    unsigned short* bufH_r = (unsigned short*)carve((size_t)N_NODES * H_DIM * 2);

    hipMemsetAsync(zstart, 0, zbytes, stream);

    // 1. histL || histR || wconv || xconvL || xconvR
    k_hist2<<<2 * EG + WCONV_BLKS + 2 * XC_BLKS, 256, 0, stream>>>(
        src_l, dst_l, cs_l, fc_l, rk_l,
        src_r, dst_r, cs_r, fc_r, rk_r,
        W0, W1, W2, Wt,
        xl, xp_l, xr, xp_r);

    // 2. degrees + scans
    deg_scan1_kernel<<<dim3(SCAN_BLOCKS, 2), 256, 0, stream>>>(
        cs_l, fc_l, dso_l, dsi_l, rp_l, bs_l,
        cs_r, fc_r, dso_r, dsi_r, rp_r, bs_r);
    scan2_kernel<<<dim3(1, 2), 256, 0, stream>>>(bs_l, bs_r, SCAN_BLOCKS);
    scan3_kernel<<<dim3(SCAN_BLOCKS, 2), 256, 0, stream>>>(rp_l, bs_l, rp_r, bs_r);

    // 3. scatL || scatR
    k_scat2<<<2 * EG, 256, 0, stream>>>(
        src_l, dst_l, rp_l, rk_l, col_l,
        src_r, dst_r, rp_r, rk_r, col_r);

    // 4. layer 0 (agg gathers dso per edge)
    fuse_agg2_l0<<<2 * AGG0_BLKS, 256, 0, stream>>>(
        xp_l, dso_l, rp_l, col_l, bufA_l,
        xp_r, dso_r, rp_r, col_r, bufA_r);
    gemm_pair2<K0, 16><<<2 * GEMM_BLKS, 256, 0, stream>>>(
        bufA_l, dsi_l, dso_l, bufH_l,
        bufA_r, dsi_r, dso_r, bufH_r,
        Wt0, b0);

    // 5. layer 1
    fuse_agg2_h<<<2 * AGGH_BLKS, 256, 0, stream>>>(
        bufH_l, rp_l, col_l, bufA_l,
        bufH_r, rp_r, col_r, bufA_r);
    gemm_pair2<H_DIM, 32><<<2 * GEMM_BLKS, 256, 0, stream>>>(
        bufA_l, dsi_l, dso_l, bufH_l,
        bufA_r, dsi_r, dso_r, bufH_r,
        Wt1, b1);

    // 6. layer 2
    fuse_agg2_h<<<2 * AGGH_BLKS, 256, 0, stream>>>(
        bufH_l, rp_l, col_l, bufA_l,
        bufH_r, rp_r, col_r, bufA_r);
    gemm_pair2<H_DIM, 32><<<2 * GEMM_BLKS, 256, 0, stream>>>(
        bufA_l, dsi_l, nullptr, bufH_l,
        bufA_r, dsi_r, nullptr, bufH_r,
        Wt2, b2);

    // 7. pools + MLP
    pool2_kernel<<<2 * POOL_BLKS, 256, 0, stream>>>(
        bufH_l, gid_l, pool_l,
        bufH_r, gid_r, pool_r);
    mlp_kernel<<<N_GRAPHS, 256, 0, stream>>>(pool_l, pool_r, Wf1, bf1, Wf2, bf2, out);
}

// Round 13
// 737.804 us; speedup vs baseline: 1.0570x; 1.0570x over previous
//
#include <hip/hip_runtime.h>

#define N_NODES 50000
#define N_EDGES 800000
#define N_GRAPHS 100
#define FIN_DIM 74
#define K0 96              // layer-0 K (padded), 6 slices of 16
#define H_DIM 256          // hidden width, 8 slices of 32
#define EG 3125            // N_EDGES / 256
#define XS2_BLKS 9375      // N_NODES*48/256 (float2-vectorized xscale)
#define WCONV_BLKS 608     // (256*96 + 2*256*256)/256
#define AGG0_BLKS 3128     // 391 node-groups * 8 slices
#define AGGH_BLKS 6256     // 782 * 8
#define GEMM_BLKS 782      // 391 m-tiles * 2 n-tiles
#define POOL_BLKS 782
#define SCAN_BLOCKS 196

typedef float f32x4 __attribute__((ext_vector_type(4)));
typedef float f32x2 __attribute__((ext_vector_type(2)));
typedef unsigned int u32x4 __attribute__((ext_vector_type(4)));
typedef unsigned short us2 __attribute__((ext_vector_type(2)));
typedef unsigned short us8 __attribute__((ext_vector_type(8)));
typedef __bf16 bf16x8 __attribute__((ext_vector_type(8)));

__device__ __forceinline__ unsigned short f2bf(float x) {
    unsigned u = __builtin_bit_cast(unsigned, x);
    u += 0x7fff + ((u >> 16) & 1);
    return (unsigned short)(u >> 16);
}
__device__ __forceinline__ float bf2f(unsigned short h) {
    return __builtin_bit_cast(float, (unsigned)h << 16);
}
__device__ __forceinline__ void acc8(float* a, us8 v) {
    u32x4 w = __builtin_bit_cast(u32x4, v);
    #pragma unroll
    for (int i = 0; i < 4; ++i) {
        a[2 * i]     += __builtin_bit_cast(float, w[i] << 16);
        a[2 * i + 1] += __builtin_bit_cast(float, w[i] & 0xffff0000u);
    }
}

// ================= device bodies (R9/R10-proven) =================

__device__ __forceinline__ void hist_body(int bid, const int* __restrict__ src,
                                          const int* __restrict__ dst,
                                          int* __restrict__ cs, int* __restrict__ fc,
                                          int* __restrict__ rk) {
    int e = bid * 256 + threadIdx.x;
    if (e < N_EDGES) {
        rk[e] = atomicAdd(&fc[dst[e]], 1);
        atomicAdd(&cs[src[e]], 1);
    }
}

__device__ __forceinline__ void scat_body(int bid, const int* __restrict__ src,
                                          const int* __restrict__ dst,
                                          const int* __restrict__ rp,
                                          const int* __restrict__ rk,
                                          int* __restrict__ col) {
    int e = bid * 256 + threadIdx.x;
    if (e < N_EDGES) {
        int d = dst[e];
        col[rp[d] + rk[e]] = src[e];
    }
}

// x' = bf16(x*dso), slice-major [6][N][16]; float2-vectorized (2 feats/thread)
__device__ __forceinline__ void xscale_body(int bid, const float* __restrict__ x,
                                            const float* __restrict__ dso,
                                            unsigned short* __restrict__ xp) {
    int id = bid * 256 + threadIdx.x;           // over N*48 pairs
    int n = id / 48, f = (id - n * 48) * 2;     // f even, 0..94
    float v0 = 0.f, v1 = 0.f;
    if (f < FIN_DIM) {                          // f<=72 -> f+1<=73<74: both valid
        f32x2 t = *(const f32x2*)&x[(size_t)n * FIN_DIM + f];
        float d = dso[n];
        v0 = t[0] * d; v1 = t[1] * d;
    }
    us2 r = { f2bf(v0), f2bf(v1) };
    *(us2*)&xp[(size_t)(f >> 4) * (N_NODES * 16) + (size_t)n * 16 + (f & 15)] = r;
}

__device__ __forceinline__ void wconv_body(int bid, const float* __restrict__ W0,
                                           const float* __restrict__ W1,
                                           const float* __restrict__ W2,
                                           unsigned short* __restrict__ Wt) {
    int id = bid * 256 + threadIdx.x;
    if (id < 256 * 96) {
        int n = id / 96, k = id - n * 96;
        float v = (k < FIN_DIM) ? W0[(size_t)k * H_DIM + n] : 0.f;
        Wt[id] = f2bf(v);
    } else if (id < 256 * 96 + 65536) {
        int id2 = id - 256 * 96;
        int n = id2 >> 8, k = id2 & 255;
        Wt[id] = f2bf(W1[(size_t)k * H_DIM + n]);
    } else {
        int id3 = id - 256 * 96 - 65536;
        int n = id3 >> 8, k = id3 & 255;
        Wt[id] = f2bf(W2[(size_t)k * H_DIM + n]);
    }
}

// XCD-sliced aggregate, ILP-4 (proven best); cg = slice index
template<int SW, int NACT, int NSL>
__device__ __forceinline__ void agg_body(int abid, int cg,
                                         const unsigned short* __restrict__ h,
                                         const int* __restrict__ rp,
                                         const int* __restrict__ col,
                                         unsigned short* __restrict__ A) {
    const int CPB = SW / 8;
    const int NPB = 256 / CPB;
    if (cg >= NSL) return;
    int slot = threadIdx.x & (CPB - 1);
    int n = (abid >> 3) * NPB + threadIdx.x / CPB;
    if (n >= N_NODES) return;
    unsigned short* dst = A + (size_t)cg * (N_NODES * SW) + (size_t)n * SW + slot * 8;
    if (cg >= NACT) { us8 z = {}; *(us8*)dst = z; return; }
    const unsigned short* hs = h + (size_t)cg * (N_NODES * SW) + slot * 8;
    int beg = rp[n], end = rp[n + 1];
    float a[8] = {};
    int j = beg;
    for (; j + 3 < end; j += 4) {
        int s0 = col[j], s1 = col[j + 1], s2 = col[j + 2], s3 = col[j + 3];
        us8 v0 = *(const us8*)(hs + (size_t)s0 * SW);
        us8 v1 = *(const us8*)(hs + (size_t)s1 * SW);
        us8 v2 = *(const us8*)(hs + (size_t)s2 * SW);
        us8 v3 = *(const us8*)(hs + (size_t)s3 * SW);
        acc8(a, v0); acc8(a, v1); acc8(a, v2); acc8(a, v3);
    }
    for (; j < end; ++j)
        acc8(a, *(const us8*)(hs + (size_t)col[j] * SW));
    us8 r;
    #pragma unroll
    for (int i = 0; i < 8; ++i) r[i] = f2bf(a[i]);
    *(us8*)dst = r;
}

__device__ __forceinline__ void pool_body(int nb, const unsigned short* __restrict__ h,
                                          const int* __restrict__ gid,
                                          float* __restrict__ pool) {
    int n0 = nb * 64;
    int f = threadIdx.x;
    const unsigned short* hf = h + (size_t)(f >> 5) * (N_NODES * 32) + (f & 31);
    int end = min(n0 + 64, N_NODES);
    float acc = 0.0f;
    int gcur = gid[n0];
    for (int i = n0; i < end; ++i) {
        int g = gid[i];
        if (g != gcur) {
            atomicAdd(&pool[(size_t)gcur * H_DIM + f], acc);
            acc = 0.0f;
            gcur = g;
        }
        acc += bf2f(hf[(size_t)i * 32]);
    }
    atomicAdd(&pool[(size_t)gcur * H_DIM + f], acc);
}

// MFMA GEMM (R9-proven, full B staging)
template<int K, int SW>
__device__ __forceinline__ void gemm_body(int id, const unsigned short* __restrict__ A,
                                          const unsigned short* __restrict__ Wt,
                                          const float* __restrict__ bias,
                                          const float* __restrict__ dsi,
                                          const float* __restrict__ scale,
                                          unsigned short* __restrict__ C,
                                          unsigned short* smem) {
    unsigned short (*Ah)[40] = (unsigned short(*)[40])smem;
    unsigned short (*Bh)[40] = (unsigned short(*)[40])(smem + 128 * 40);
    const int M = N_NODES;

    int tid = threadIdx.x;
    int lane = tid & 63, wid = tid >> 6;
    int wm = (wid >> 1) * 64, wn = (wid & 1) * 64;
    int bm = (id >> 1) * 128, bn = (id & 1) * 128;

    f32x4 acc[4][4] = {};
    int r0 = wm + (lane & 15);
    int c0 = wn + (lane & 15);
    int kA = (lane >> 4) * 8;

    for (int k0 = 0; k0 < K; k0 += 32) {
        #pragma unroll
        for (int i = 0; i < 2; ++i) {
            int q = tid + i * 256;
            int row = q >> 2, k8 = (q & 3) * 8;
            int gm = bm + row;
            int kk = k0 + k8;
            us8 v = {};
            if (gm < M)
                v = *(const us8*)(A + (size_t)(kk / SW) * ((size_t)N_NODES * SW)
                                    + (size_t)gm * SW + (kk % SW));
            *(us8*)&Ah[row][k8] = v;
        }
        {
            int colx = tid & 127, kg = tid >> 7;
            const unsigned short* wsrc = Wt + (size_t)(bn + colx) * K + k0 + kg * 16;
            us8 w0 = *(const us8*)(wsrc);
            us8 w1 = *(const us8*)(wsrc + 8);
            *(us8*)&Bh[colx][kg * 16] = w0;
            *(us8*)&Bh[colx][kg * 16 + 8] = w1;
        }
        __syncthreads();

        bf16x8 ah[4], bh[4];
        #pragma unroll
        for (int m = 0; m < 4; ++m)
            ah[m] = __builtin_bit_cast(bf16x8, *(const us8*)&Ah[r0 + m * 16][kA]);
        #pragma unroll
        for (int n = 0; n < 4; ++n)
            bh[n] = __builtin_bit_cast(bf16x8, *(const us8*)&Bh[c0 + n * 16][kA]);

        #pragma unroll
        for (int m = 0; m < 4; ++m)
            #pragma unroll
            for (int n = 0; n < 4; ++n)
                acc[m][n] = __builtin_amdgcn_mfma_f32_16x16x32_bf16(ah[m], bh[n], acc[m][n], 0, 0, 0);
        __syncthreads();
    }

    int rowq = (lane >> 4) * 4;
    #pragma unroll
    for (int n = 0; n < 4; ++n) {
        int gn = bn + wn + n * 16 + (lane & 15);
        float bv = bias[gn];
        unsigned short* cs = C + (size_t)(gn >> 5) * (N_NODES * 32) + (gn & 31);
        #pragma unroll
        for (int m = 0; m < 4; ++m) {
            #pragma unroll
            for (int j = 0; j < 4; ++j) {
                int gm = bm + wm + m * 16 + rowq + j;
                if (gm < M) {
                    float r = fmaxf(acc[m][n][j] * dsi[gm] + bv, 0.0f);
                    if (scale) r *= scale[gm];
                    cs[(size_t)gm * 32] = f2bf(r);
                }
            }
        }
    }
}

// ================= kernels =================

__device__ __forceinline__ int block_excl_scan(int v, int* wsums) {
    int lane = threadIdx.x & 63, w = threadIdx.x >> 6;
    int x = v;
    #pragma unroll
    for (int ofs = 1; ofs < 64; ofs <<= 1) {
        int y = __shfl_up(x, ofs, 64);
        if (lane >= ofs) x += y;
    }
    if (lane == 63) wsums[w] = x;
    __syncthreads();
    int wo = 0;
    #pragma unroll
    for (int k = 0; k < 4; ++k) if (k < w) wo += wsums[k];
    return wo + x - v;
}

// wconv || histL || histR (only the small wconv rides; xconv proven non-free)
__global__ void k_hist2(const float* __restrict__ W0, const float* __restrict__ W1,
                        const float* __restrict__ W2, unsigned short* __restrict__ Wt,
                        const int* __restrict__ srcL, const int* __restrict__ dstL,
                        int* __restrict__ csL, int* __restrict__ fcL, int* __restrict__ rkL,
                        const int* __restrict__ srcR, const int* __restrict__ dstR,
                        int* __restrict__ csR, int* __restrict__ fcR, int* __restrict__ rkR) {
    int bid = blockIdx.x;
    if (bid < WCONV_BLKS)           wconv_body(bid, W0, W1, W2, Wt);
    else if (bid < WCONV_BLKS + EG) hist_body(bid - WCONV_BLKS, srcL, dstL, csL, fcL, rkL);
    else                            hist_body(bid - WCONV_BLKS - EG, srcR, dstR, csR, fcR, rkR);
}

__global__ void deg_scan1_kernel(const int* __restrict__ csL, const int* __restrict__ fcL,
                                 float* __restrict__ dsoL, float* __restrict__ dsiL,
                                 int* __restrict__ rpL, int* __restrict__ bsL,
                                 const int* __restrict__ csR, const int* __restrict__ fcR,
                                 float* __restrict__ dsoR, float* __restrict__ dsiR,
                                 int* __restrict__ rpR, int* __restrict__ bsR) {
    const int* cs = blockIdx.y ? csR : csL;
    const int* fc = blockIdx.y ? fcR : fcL;
    float* dso = blockIdx.y ? dsoR : dsoL;
    float* dsi = blockIdx.y ? dsiR : dsiL;
    int* rp = blockIdx.y ? rpR : rpL;
    int* bs = blockIdx.y ? bsR : bsL;
    __shared__ int ws[4];
    int i = blockIdx.x * 256 + threadIdx.x;
    int v = 0;
    if (i < N_NODES) {
        dso[i] = rsqrtf(fmaxf((float)cs[i], 1.0f));
        v = fc[i];
        dsi[i] = rsqrtf(fmaxf((float)v, 1.0f));
    }
    int ex = block_excl_scan(v, ws);
    if (i < N_NODES) rp[i] = ex;
    if (threadIdx.x == 255) bs[blockIdx.x] = ex + v;
}

// merged scan2+scan3: each block computes its own offset from raw bs (196 entries)
__global__ void scan23_kernel(int* __restrict__ rpL, const int* __restrict__ bsL,
                              int* __restrict__ rpR, const int* __restrict__ bsR) {
    int* rp = blockIdx.y ? rpR : rpL;
    const int* bs = blockIdx.y ? bsR : bsL;
    __shared__ int ws[4];
    __shared__ int s_off;
    int b = blockIdx.x;
    int v = (threadIdx.x < b && threadIdx.x < SCAN_BLOCKS) ? bs[threadIdx.x] : 0;
    int ex = block_excl_scan(v, ws);
    if (threadIdx.x == 255) s_off = ex + v;   // total = sum_{k<b} bs[k]
    __syncthreads();
    int i = b * 256 + threadIdx.x;
    if (i < N_NODES) rp[i] += s_off;
    if (i == 0) rp[N_NODES] = N_EDGES;
}

// scatL || scatR || xscaleL || xscaleR
__global__ void fuse_ssxx(const int* __restrict__ srcL, const int* __restrict__ dstL,
                          const int* __restrict__ rpL, const int* __restrict__ rkL,
                          int* __restrict__ colL,
                          const int* __restrict__ srcR, const int* __restrict__ dstR,
                          const int* __restrict__ rpR, const int* __restrict__ rkR,
                          int* __restrict__ colR,
                          const float* __restrict__ xL, const float* __restrict__ dsoL,
                          unsigned short* __restrict__ xpL,
                          const float* __restrict__ xR, const float* __restrict__ dsoR,
                          unsigned short* __restrict__ xpR) {
    int bid = blockIdx.x;
    if (bid < EG)                         scat_body(bid, srcL, dstL, rpL, rkL, colL);
    else if (bid < 2 * EG)                scat_body(bid - EG, srcR, dstR, rpR, rkR, colR);
    else if (bid < 2 * EG + XS2_BLKS)     xscale_body(bid - 2 * EG, xL, dsoL, xpL);
    else                                  xscale_body(bid - 2 * EG - XS2_BLKS, xR, dsoR, xpR);
}

// layer-0 agg pair
__global__ void fuse_agg2_l0(const unsigned short* __restrict__ hL, const int* __restrict__ rpL,
                             const int* __restrict__ colL, unsigned short* __restrict__ AL,
                             const unsigned short* __restrict__ hR, const int* __restrict__ rpR,
                             const int* __restrict__ colR, unsigned short* __restrict__ AR) {
    int bid = blockIdx.x;
    if (bid < AGG0_BLKS) agg_body<16, 5, 6>(bid, bid & 7, hL, rpL, colL, AL);
    else {
        int lb = bid - AGG0_BLKS;
        agg_body<16, 5, 6>(lb, lb & 7, hR, rpR, colR, AR);
    }
}

// hidden agg pair (merged form; R11 proved half-slice split neutral)
__global__ void fuse_agg2_h(const unsigned short* __restrict__ hL, const int* __restrict__ rpL,
                            const int* __restrict__ colL, unsigned short* __restrict__ AL,
                            const unsigned short* __restrict__ hR, const int* __restrict__ rpR,
                            const int* __restrict__ colR, unsigned short* __restrict__ AR) {
    int bid = blockIdx.x;
    if (bid < AGGH_BLKS) agg_body<32, 8, 8>(bid, bid & 7, hL, rpL, colL, AL);
    else {
        int lb = bid - AGGH_BLKS;
        agg_body<32, 8, 8>(lb, lb & 7, hR, rpR, colR, AR);
    }
}

template<int K, int SW>
__global__ __launch_bounds__(256) void gemm_pair2(
        const unsigned short* __restrict__ AL, const float* __restrict__ dsiL,
        const float* __restrict__ scL, unsigned short* __restrict__ CL,
        const unsigned short* __restrict__ AR, const float* __restrict__ dsiR,
        const float* __restrict__ scR, unsigned short* __restrict__ CR,
        const unsigned short* __restrict__ Wt, const float* __restrict__ bias) {
    __shared__ unsigned short smem[2 * 128 * 40];
    int bid = blockIdx.x;
    if (bid < GEMM_BLKS) gemm_body<K, SW>(bid, AL, Wt, bias, dsiL, scL, CL, smem);
    else                 gemm_body<K, SW>(bid - GEMM_BLKS, AR, Wt, bias, dsiR, scR, CR, smem);
}

__global__ void pool2_kernel(const unsigned short* __restrict__ hL, const int* __restrict__ gidL,
                             float* __restrict__ poolL,
                             const unsigned short* __restrict__ hR, const int* __restrict__ gidR,
                             float* __restrict__ poolR) {
    int bid = blockIdx.x;
    if (bid < POOL_BLKS) pool_body(bid, hL, gidL, poolL);
    else                 pool_body(bid - POOL_BLKS, hR, gidR, poolR);
}

__global__ __launch_bounds__(256) void mlp_kernel(
        const float* __restrict__ pl, const float* __restrict__ pr,
        const float* __restrict__ Wf1, const float* __restrict__ bf1,
        const float* __restrict__ Wf2, const float* __restrict__ bf2,
        float* __restrict__ out) {
    __shared__ float z[512];
    __shared__ float red[256];
    int g = blockIdx.x, tid = threadIdx.x;
    z[tid] = pl[(size_t)g * H_DIM + tid];
    z[tid + 256] = pr[(size_t)g * H_DIM + tid];
    __syncthreads();
    float t = bf1[tid];
    #pragma unroll 8
    for (int k = 0; k < 512; ++k) t += z[k] * Wf1[(size_t)k * H_DIM + tid];
    t = fmaxf(t, 0.0f);
    red[tid] = t * Wf2[tid];
    __syncthreads();
    for (int ofs = 128; ofs > 0; ofs >>= 1) {
        if (tid < ofs) red[tid] += red[tid + ofs];
        __syncthreads();
    }
    if (tid == 0) out[g] = red[0] + bf2[0];
}

// ================= driver =================

extern "C" void kernel_launch(void* const* d_in, const int* in_sizes, int n_in,
                              void* d_out, int out_size, void* d_ws, size_t ws_size,
                              hipStream_t stream) {
    const float* xl   = (const float*)d_in[0];
    const float* xr   = (const float*)d_in[1];
    const int* src_l  = (const int*)d_in[2];
    const int* dst_l  = (const int*)d_in[3];
    const int* src_r  = (const int*)d_in[4];
    const int* dst_r  = (const int*)d_in[5];
    const int* gid_l  = (const int*)d_in[6];
    const int* gid_r  = (const int*)d_in[7];
    const float* W0   = (const float*)d_in[8];
    const float* b0   = (const float*)d_in[9];
    const float* W1   = (const float*)d_in[10];
    const float* b1   = (const float*)d_in[11];
    const float* W2   = (const float*)d_in[12];
    const float* b2   = (const float*)d_in[13];
    const float* Wf1  = (const float*)d_in[14];
    const float* bf1  = (const float*)d_in[15];
    const float* Wf2  = (const float*)d_in[16];
    const float* bf2  = (const float*)d_in[17];
    float* out = (float*)d_out;
    (void)in_sizes; (void)n_in; (void)out_size; (void)ws_size;

    size_t off = 0;
    auto carve = [&](size_t bytes) {
        void* p = (char*)d_ws + off;
        off += (bytes + 255) & ~(size_t)255;
        return p;
    };
    const size_t NB4 = (size_t)N_NODES * 4;

    // zero zone (single memset)
    char* zstart = (char*)d_ws;
    int*   cs_l   = (int*)carve(NB4);
    int*   fc_l   = (int*)carve(NB4);
    int*   cs_r   = (int*)carve(NB4);
    int*   fc_r   = (int*)carve(NB4);
    float* pool_l = (float*)carve((size_t)N_GRAPHS * H_DIM * 4);
    float* pool_r = (float*)carve((size_t)N_GRAPHS * H_DIM * 4);
    size_t zbytes = off;

    float* dso_l = (float*)carve(NB4);
    float* dsi_l = (float*)carve(NB4);
    float* dso_r = (float*)carve(NB4);
    float* dsi_r = (float*)carve(NB4);
    int*   rp_l  = (int*)carve((size_t)(N_NODES + 1) * 4);
    int*   rp_r  = (int*)carve((size_t)(N_NODES + 1) * 4);
    int*   col_l = (int*)carve((size_t)N_EDGES * 4);
    int*   col_r = (int*)carve((size_t)N_EDGES * 4);
    int*   rk_l  = (int*)carve((size_t)N_EDGES * 4);
    int*   rk_r  = (int*)carve((size_t)N_EDGES * 4);
    int*   bs_l  = (int*)carve((size_t)SCAN_BLOCKS * 4);
    int*   bs_r  = (int*)carve((size_t)SCAN_BLOCKS * 4);

    unsigned short* Wt    = (unsigned short*)carve((size_t)(256 * 96 + 2 * 65536) * 2);
    unsigned short* Wt0   = Wt;
    unsigned short* Wt1   = Wt + 256 * 96;
    unsigned short* Wt2   = Wt + 256 * 96 + 65536;
    unsigned short* xp_l  = (unsigned short*)carve((size_t)N_NODES * 96 * 2);
    unsigned short* xp_r  = (unsigned short*)carve((size_t)N_NODES * 96 * 2);
    unsigned short* bufA_l = (unsigned short*)carve((size_t)N_NODES * H_DIM * 2);
    unsigned short* bufA_r = (unsigned short*)carve((size_t)N_NODES * H_DIM * 2);
    unsigned short* bufH_l = (unsigned short*)carve((size_t)N_NODES * H_DIM * 2);
    unsigned short* bufH_r = (unsigned short*)carve((size_t)N_NODES * H_DIM * 2);

    hipMemsetAsync(zstart, 0, zbytes, stream);

    // 1. wconv || histL || histR
    k_hist2<<<WCONV_BLKS + 2 * EG, 256, 0, stream>>>(
        W0, W1, W2, Wt,
        src_l, dst_l, cs_l, fc_l, rk_l,
        src_r, dst_r, cs_r, fc_r, rk_r);

    // 2. degrees + scans (scan2 merged into scan23)
    deg_scan1_kernel<<<dim3(SCAN_BLOCKS, 2), 256, 0, stream>>>(
        cs_l, fc_l, dso_l, dsi_l, rp_l, bs_l,
        cs_r, fc_r, dso_r, dsi_r, rp_r, bs_r);
    scan23_kernel<<<dim3(SCAN_BLOCKS, 2), 256, 0, stream>>>(rp_l, bs_l, rp_r, bs_r);

    // 3. scatL || scatR || xscaleL || xscaleR
    fuse_ssxx<<<2 * EG + 2 * XS2_BLKS, 256, 0, stream>>>(
        src_l, dst_l, rp_l, rk_l, col_l,
        src_r, dst_r, rp_r, rk_r, col_r,
        xl, dso_l, xp_l,
        xr, dso_r, xp_r);

    // 4. layer 0
    fuse_agg2_l0<<<2 * AGG0_BLKS, 256, 0, stream>>>(
        xp_l, rp_l, col_l, bufA_l,
        xp_r, rp_r, col_r, bufA_r);
    gemm_pair2<K0, 16><<<2 * GEMM_BLKS, 256, 0, stream>>>(
        bufA_l, dsi_l, dso_l, bufH_l,
        bufA_r, dsi_r, dso_r, bufH_r,
        Wt0, b0);

    // 5. layer 1
    fuse_agg2_h<<<2 * AGGH_BLKS, 256, 0, stream>>>(
        bufH_l, rp_l, col_l, bufA_l,
        bufH_r, rp_r, col_r, bufA_r);
    gemm_pair2<H_DIM, 32><<<2 * GEMM_BLKS, 256, 0, stream>>>(
        bufA_l, dsi_l, dso_l, bufH_l,
        bufA_r, dsi_r, dso_r, bufH_r,
        Wt1, b1);

    // 6. layer 2
    fuse_agg2_h<<<2 * AGGH_BLKS, 256, 0, stream>>>(
        bufH_l, rp_l, col_l, bufA_l,
        bufH_r, rp_r, col_r, bufA_r);
    gemm_pair2<H_DIM, 32><<<2 * GEMM_BLKS, 256, 0, stream>>>(
        bufA_l, dsi_l, nullptr, bufH_l,
        bufA_r, dsi_r, nullptr, bufH_r,
        Wt2, b2);

    // 7. pools + MLP
    pool2_kernel<<<2 * POOL_BLKS, 256, 0, stream>>>(
        bufH_l, gid_l, pool_l,
        bufH_r, gid_r, pool_r);
    mlp_kernel<<<N_GRAPHS, 256, 0, stream>>>(pool_l, pool_r, Wf1, bf1, Wf2, bf2, out);
}